// Round 13
// baseline (7100.997 us; speedup 1.0000x reference)
//
#include <hip/hip_runtime.h>
#include <cstdint>

// Reference semantics (validated, absmax=0.0 — DO NOT change arithmetic):
//  - selection on RAW f32 coords, distance = fma(dz,dz, fma(dx,dx, dy*dy))
//    with dx/dy/dz plain f32 subs;
//  - min/argmax exact, FIRST-index tie-break (min global point index);
//  - output coords bf16-RNE-rounded, batch = float b.
//
// R24: R23 (fused scan + pk-sub) regressed -> reverted to R19 base (5417us,
// best). R19's remaining cost anatomy: ~900cyc UPD issue + ~300 reduce +
// ~350-450cyc SERIAL post-barrier tail (key ds_read ~120 -> DPP -> s_xy[gu]
// broadcast ~120 -> cz global ~200, all chained, shared by every wave).
// Fix: per-wave candidate publish. Before the barrier the publishing wave
// (winner is always in-wave: idx = slot*1024+t) prefetches winner x,y from
// s_xy (uniform ds_read, hidden under barrier skew), slot-selects winner z
// from its pz registers + 1 readlane, and lane0 writes Cand{x,y,z} (16B)
// beside the key. Post-barrier: key+cand read together (one LDS latency),
// DPP key finalize, then 3 readlanes = center. s_xy[gu] and the cz global
// load disappear from the critical path. Publish/readlane machinery was
// validated end-to-end in R21 (absmax 0.0). Everything else is R19.
#pragma clang fp contract(off)

#define B_ 16
#define N_ 16384
#define K_ 4096
#define THREADS_ 1024
#define NW_ (THREADS_ / 64)    // 16 waves per block

#define PTS_LIST(X) \
  X(0) X(1) X(2) X(3) X(4) X(5) X(6) X(7) \
  X(8) X(9) X(10) X(11) X(12) X(13) X(14) X(15)

// f32 -> bf16 RNE, returned as the bf16-representable f32 (finite inputs)
__device__ __forceinline__ float bfr(float f) {
  union { float f; uint32_t i; } c; c.f = f;
  c.i = (c.i + 0x7FFFu + ((c.i >> 16) & 1u)) & 0xFFFF0000u;
  return c.f;
}

// ---- DPP helpers (ctrl is a template constant) -----------------------------
template <int CTRL>
__device__ __forceinline__ float dpp_fmax(float v) {
  union { float f; int i; } s, p;
  s.f = v;
  p.i = __builtin_amdgcn_update_dpp(0, s.i, CTRL, 0xF, 0xF, false);
  return fmaxf(v, p.f);
}
template <int CTRL>
__device__ __forceinline__ unsigned dpp_umin(unsigned v) {
  const int p = __builtin_amdgcn_update_dpp((int)0xFFFFFFFFu, (int)v,
                                            CTRL, 0xF, 0xF, false);
  const unsigned pu = (unsigned)p;
  return pu < v ? pu : v;
}

// wave-wide (max bv, min bg among maxed) -> (wv, wg), uniform in all lanes.
__device__ __forceinline__ void wave_argmax(float bv, unsigned bg,
                                            float& wv, unsigned& wg) {
  float v = bv;
  v = dpp_fmax<0x111>(v);  // row_shr:1
  v = dpp_fmax<0x112>(v);  // row_shr:2
  v = dpp_fmax<0x114>(v);  // row_shr:4
  v = dpp_fmax<0x118>(v);  // row_shr:8
  v = dpp_fmax<0x142>(v);  // row_bcast:15
  v = dpp_fmax<0x143>(v);  // row_bcast:31
  union { float f; int i; } mx;
  mx.i = __builtin_amdgcn_readlane(__builtin_bit_cast(int, v), 63);
  unsigned c = (bv == mx.f) ? bg : 0xFFFFFFFFu;
  c = dpp_umin<0x111>(c);
  c = dpp_umin<0x112>(c);
  c = dpp_umin<0x114>(c);
  c = dpp_umin<0x118>(c);
  c = dpp_umin<0x142>(c);
  c = dpp_umin<0x143>(c);
  wg = (unsigned)__builtin_amdgcn_readlane((int)c, 63);
  wv = mx.f;
}

// u64 key max over a DPP lane-permutation (block-finalize butterfly; key is
// (f32bits(dist)<<32)|~idx so u64 max == (max dist, min index)). Exact.
template <int CTRL>
__device__ __forceinline__ unsigned long long kmax_dpp(unsigned long long k) {
  const int lo = (int)(unsigned)k;
  const int hi = (int)(unsigned)(k >> 32);
  const int plo = __builtin_amdgcn_update_dpp(lo, lo, CTRL, 0xF, 0xF, true);
  const int phi = __builtin_amdgcn_update_dpp(hi, hi, CTRL, 0xF, 0xF, true);
  const unsigned long long ok =
      ((unsigned long long)(unsigned)phi << 32) | (unsigned)plo;
  return ok > k ? ok : k;
}

struct alignas(16) Cand { float x, y, z, pad; };

__global__ __attribute__((amdgpu_flat_work_group_size(THREADS_, THREADS_),
                          amdgpu_waves_per_eu(4, 4)))
void fps_kernel(const float* __restrict__ x, float* __restrict__ out)
{
#pragma clang fp contract(off)
  const int b    = blockIdx.x;
  const int t    = threadIdx.x;
  const int lane = t & 63;
  const int wave = t >> 6;

  // x,y of all 16384 points (128 KB). Thread t reads only slots {i*1024+t}
  // in the update loop; publish-phase reads are uniform-address broadcasts.
  __shared__ float2 s_xy[N_];
  // parity-double-buffered per-wave argmax keys + winner-coord records
  __shared__ unsigned long long s_key[2][NW_];
  __shared__ Cand               s_cand[2][NW_];

  const float* xb  = x + (size_t)b * (N_ * 3);
  float* out_x     = out;                        // [B*K*3] f32 (bf16-grid values)
  float* out_batch = out + (size_t)B_ * K_ * 3;  // [B*K]   f32 cloud ids

  // batch output (buffer re-poisoned every call -> rewrite every call)
  {
    const float bb = (float)b;
    for (int i = t; i < K_; i += THREADS_) out_batch[b * K_ + i] = bb;
  }

  // z and running-min in named registers; x,y staged to LDS
#define DECLP(i) float pz##i, m##i;
  PTS_LIST(DECLP)
#undef DECLP

#define LOADP(i) { const float* p_ = xb + 3 * ((i) * THREADS_ + t); \
                   float2 v_; v_.x = p_[0]; v_.y = p_[1];           \
                   s_xy[(i) * THREADS_ + t] = v_;                   \
                   pz##i = p_[2]; m##i = __builtin_inff(); }
  PTS_LIST(LOADP)
#undef LOADP

  // dist update (bit-exact FMA-V1), min into m##i; x,y from LDS (same bits)
#define UPD(i) { const float2 v_ = s_xy[(i) * THREADS_ + t];                    \
                 const float dx_ = v_.x - cx;                                   \
                 const float dy_ = v_.y - cy;                                   \
                 const float dz_ = pz##i - cz;                                  \
                 const float d_  = __builtin_fmaf(dz_, dz_,                     \
                                   __builtin_fmaf(dx_, dx_, dy_ * dy_));        \
                 m##i = fminf(m##i, d_); }

  // max3 tree over the 16 m values; value identical to sequential max.
#define MAXTREE(M_) { const float t0_ = fmaxf(fmaxf(m0,  m1),  m2);  \
                      const float t1_ = fmaxf(fmaxf(m3,  m4),  m5);  \
                      const float t2_ = fmaxf(fmaxf(m6,  m7),  m8);  \
                      const float t3_ = fmaxf(fmaxf(m9,  m10), m11); \
                      const float t4_ = fmaxf(fmaxf(m12, m13), m14); \
                      const float u0_ = fmaxf(fmaxf(t0_, t1_), t2_); \
                      const float u1_ = fmaxf(fmaxf(t3_, t4_), m15); \
                      M_ = fmaxf(u0_, u1_); }

  // descending equality chain: final bs = smallest slot with m==M
#define IDXCHAIN(M_, BS_) { BS_ = 15;                                \
      if (m14 == M_) BS_ = 14; if (m13 == M_) BS_ = 13;              \
      if (m12 == M_) BS_ = 12; if (m11 == M_) BS_ = 11;              \
      if (m10 == M_) BS_ = 10; if (m9  == M_) BS_ = 9;               \
      if (m8  == M_) BS_ = 8;  if (m7  == M_) BS_ = 7;               \
      if (m6  == M_) BS_ = 6;  if (m5  == M_) BS_ = 5;               \
      if (m4  == M_) BS_ = 4;  if (m3  == M_) BS_ = 3;               \
      if (m2  == M_) BS_ = 2;  if (m1  == M_) BS_ = 1;               \
      if (m0  == M_) BS_ = 0; }

  // per-thread argmax -> wave argmax -> publish key + winner coords.
  // Winner idx = bs*1024 + t' is owned by a lane IN this wave:
  // owner lane = wg&63, slot = wg>>10 (both wave-uniform). x,y prefetched
  // from s_xy via uniform ds_read (latency overlaps the z select below);
  // z slot-selected from this thread's pz regs then readlane'd from the
  // owner. Pure bit-copies of the originally loaded f32 values.
#define REDUCE_AND_POST(P) {                                             \
      float bv; int bs;                                                  \
      MAXTREE(bv)                                                        \
      IDXCHAIN(bv, bs)                                                   \
      const unsigned bg = (unsigned)(bs * THREADS_ + t);                 \
      float wv; unsigned wg;                                             \
      wave_argmax(bv, bg, wv, wg);                                       \
      const unsigned wgu =                                               \
          (unsigned)__builtin_amdgcn_readfirstlane((int)wg);             \
      const float2 wxy = s_xy[wgu];          /* uniform broadcast read */\
      const unsigned su = wgu >> 10;                                     \
      float sz = pz0;                                                    \
      if (su == 1)  sz = pz1;  if (su == 2)  sz = pz2;                   \
      if (su == 3)  sz = pz3;  if (su == 4)  sz = pz4;                   \
      if (su == 5)  sz = pz5;  if (su == 6)  sz = pz6;                   \
      if (su == 7)  sz = pz7;  if (su == 8)  sz = pz8;                   \
      if (su == 9)  sz = pz9;  if (su == 10) sz = pz10;                  \
      if (su == 11) sz = pz11; if (su == 12) sz = pz12;                  \
      if (su == 13) sz = pz13; if (su == 14) sz = pz14;                  \
      if (su == 15) sz = pz15;                                           \
      const int ol_ = (int)(wgu & 63u);                                  \
      const int szi = __builtin_amdgcn_readlane(                         \
                          __builtin_bit_cast(int, sz), ol_);             \
      if (lane == 0) {                                                   \
        union { float f; unsigned u; } cv; cv.f = wv;                    \
        s_key[P][wave] =                                                 \
            ((unsigned long long)cv.u << 32) | (unsigned)~wgu;           \
        Cand c_;                                                         \
        c_.x = wxy.x; c_.y = wxy.y;                                      \
        c_.z = __builtin_bit_cast(float, szi); c_.pad = 0.0f;            \
        s_cand[P][wave] = c_;                                            \
      } }

  // ---- iteration 0: seed = point 0 ----
  float cx = xb[0], cy = xb[1], cz = xb[2];
  if (t == 0) {
    const uint64_t o = ((uint64_t)b * K_) * 3;
    out_x[o + 0] = bfr(cx); out_x[o + 1] = bfr(cy); out_x[o + 2] = bfr(cz);
  }

  PTS_LIST(UPD)                      // m_i = d_i (min with +inf)
  REDUCE_AND_POST(0)
  __syncthreads();

  // ---- iterations 1..K-1 ----
  for (int j = 1; j < K_; ++j) {
    const int rp = (j - 1) & 1;
    const int wp = j & 1;

    // finalize block argmax: key+cand of wave (lane&15) read together (one
    // LDS latency), 4 DPP levels on the key -> every lane holds the block
    // winner; center = 3 readlanes from the winning wave's record.
    unsigned long long k = s_key[rp][lane & 15];
    const Cand cd = s_cand[rp][lane & 15];
    k = kmax_dpp<0xB1>(k);    // quad_perm lane^1
    k = kmax_dpp<0x4E>(k);    // quad_perm lane^2
    k = kmax_dpp<0x141>(k);   // row_half_mirror (lane^7, covers ^4)
    k = kmax_dpp<0x140>(k);   // row_mirror (lane^15, covers ^8)
    const unsigned idx = ~(unsigned)k;           // winner global point index
    const int ws = __builtin_amdgcn_readfirstlane((int)((idx >> 6) & 15u));
    cx = __builtin_bit_cast(float,
           __builtin_amdgcn_readlane(__builtin_bit_cast(int, cd.x), ws));
    cy = __builtin_bit_cast(float,
           __builtin_amdgcn_readlane(__builtin_bit_cast(int, cd.y), ws));
    cz = __builtin_bit_cast(float,
           __builtin_amdgcn_readlane(__builtin_bit_cast(int, cd.z), ws));
    if (t == 0) {
      const uint64_t o = ((uint64_t)b * K_ + j) * 3;
      out_x[o + 0] = bfr(cx); out_x[o + 1] = bfr(cy); out_x[o + 2] = bfr(cz);
    }

    // update mind + per-thread/wave argmax + publish for next round
    PTS_LIST(UPD)
    REDUCE_AND_POST(wp)
    __syncthreads();
  }
#undef UPD
#undef MAXTREE
#undef IDXCHAIN
#undef REDUCE_AND_POST

}

extern "C" void kernel_launch(void* const* d_in, const int* in_sizes, int n_in,
                              void* d_out, int out_size, void* d_ws, size_t ws_size,
                              hipStream_t stream) {
  const float* x = (const float*)d_in[0];  // f32, [B*N, 3]
  float* out     = (float*)d_out;          // f32: [B*K*3] coords + [B*K] batch
  (void)in_sizes; (void)n_in; (void)out_size; (void)d_ws; (void)ws_size;
  hipLaunchKernelGGL(fps_kernel, dim3(B_), dim3(THREADS_), 0, stream, x, out);
}

// Round 14
// 5620.508 us; speedup vs baseline: 1.2634x; 1.2634x over previous
//
#include <hip/hip_runtime.h>
#include <cstdint>

// Reference semantics (validated, absmax=0.0 — DO NOT change arithmetic):
//  - selection on RAW f32 coords, distance = fma(dz,dz, fma(dx,dx, dy*dy))
//    with dx/dy/dz plain f32 subs;
//  - min/argmax exact, FIRST-index tie-break (min global point index);
//  - output coords bf16-RNE-rounded, batch = float b.
//
// R25: R24 (candidate publish) regressed -> reverted to R19 base (5417us).
// Five failed attempts show R19 is limited by neither VALU count nor the
// post-barrier tail. Unexamined: DS pipe. R19 issues 256 wave-level
// ds_read_b64 per CU per iteration (~6-12cyc each => 1500-3000 cyc/iter on
// the DS pipe, same order as the whole 3174-cyc iteration).
// Fix (single variable): pair-interleaved float4 LDS layout —
// s_p[pair*1024+t] = {x(2p*1024+t), y(2p*1024+t), x((2p+1)*1024+t),
// y((2p+1)*1024+t)}; one ds_read_b128 feeds TWO points -> 8 DS instr/
// thread/iter instead of 16. Consecutive 16B/lane = standard conflict-free
// b128 pattern. Per-point arithmetic, slot numbering, MAXTREE/IDXCHAIN,
// DPP wave argmax, u64-key finalize, parity buffer, one barrier/iter:
// byte-identical to R19. Center x,y = one uniform float4 read + 2 selects;
// z from global (unchanged).
#pragma clang fp contract(off)

#define B_ 16
#define N_ 16384
#define K_ 4096
#define THREADS_ 1024
#define NW_ (THREADS_ / 64)    // 16 waves per block

// pz/m declarations: 16 per-slot scalars (as R19)
#define PTS_LIST(X) \
  X(0) X(1) X(2) X(3) X(4) X(5) X(6) X(7) \
  X(8) X(9) X(10) X(11) X(12) X(13) X(14) X(15)

// pairs: (pair index, slot A = 2p, slot B = 2p+1)
#define PAIR_LIST(X) \
  X(0, 0, 1)  X(1, 2, 3)  X(2, 4, 5)  X(3, 6, 7) \
  X(4, 8, 9)  X(5, 10, 11) X(6, 12, 13) X(7, 14, 15)

// f32 -> bf16 RNE, returned as the bf16-representable f32 (finite inputs)
__device__ __forceinline__ float bfr(float f) {
  union { float f; uint32_t i; } c; c.f = f;
  c.i = (c.i + 0x7FFFu + ((c.i >> 16) & 1u)) & 0xFFFF0000u;
  return c.f;
}

// ---- DPP helpers (ctrl is a template constant) -----------------------------
template <int CTRL>
__device__ __forceinline__ float dpp_fmax(float v) {
  union { float f; int i; } s, p;
  s.f = v;
  p.i = __builtin_amdgcn_update_dpp(0, s.i, CTRL, 0xF, 0xF, false);
  return fmaxf(v, p.f);
}
template <int CTRL>
__device__ __forceinline__ unsigned dpp_umin(unsigned v) {
  const int p = __builtin_amdgcn_update_dpp((int)0xFFFFFFFFu, (int)v,
                                            CTRL, 0xF, 0xF, false);
  const unsigned pu = (unsigned)p;
  return pu < v ? pu : v;
}

// wave-wide (max bv, min bg among maxed) -> (wv, wg), uniform in all lanes.
__device__ __forceinline__ void wave_argmax(float bv, unsigned bg,
                                            float& wv, unsigned& wg) {
  float v = bv;
  v = dpp_fmax<0x111>(v);  // row_shr:1
  v = dpp_fmax<0x112>(v);  // row_shr:2
  v = dpp_fmax<0x114>(v);  // row_shr:4
  v = dpp_fmax<0x118>(v);  // row_shr:8
  v = dpp_fmax<0x142>(v);  // row_bcast:15
  v = dpp_fmax<0x143>(v);  // row_bcast:31
  union { float f; int i; } mx;
  mx.i = __builtin_amdgcn_readlane(__builtin_bit_cast(int, v), 63);
  unsigned c = (bv == mx.f) ? bg : 0xFFFFFFFFu;
  c = dpp_umin<0x111>(c);
  c = dpp_umin<0x112>(c);
  c = dpp_umin<0x114>(c);
  c = dpp_umin<0x118>(c);
  c = dpp_umin<0x142>(c);
  c = dpp_umin<0x143>(c);
  wg = (unsigned)__builtin_amdgcn_readlane((int)c, 63);
  wv = mx.f;
}

// u64 key max over a DPP lane-permutation (block-finalize butterfly; key is
// (f32bits(dist)<<32)|~idx so u64 max == (max dist, min index)). Exact.
template <int CTRL>
__device__ __forceinline__ unsigned long long kmax_dpp(unsigned long long k) {
  const int lo = (int)(unsigned)k;
  const int hi = (int)(unsigned)(k >> 32);
  const int plo = __builtin_amdgcn_update_dpp(lo, lo, CTRL, 0xF, 0xF, true);
  const int phi = __builtin_amdgcn_update_dpp(hi, hi, CTRL, 0xF, 0xF, true);
  const unsigned long long ok =
      ((unsigned long long)(unsigned)phi << 32) | (unsigned)plo;
  return ok > k ? ok : k;
}

__global__ __attribute__((amdgpu_flat_work_group_size(THREADS_, THREADS_),
                          amdgpu_waves_per_eu(4, 4)))
void fps_kernel(const float* __restrict__ x, float* __restrict__ out)
{
#pragma clang fp contract(off)
  const int b    = blockIdx.x;
  const int t    = threadIdx.x;
  const int lane = t & 63;
  const int wave = t >> 6;

  // x,y of all 16384 points in pair-interleaved float4 form (128 KB):
  // s_p[p*1024+t] = {x_a, y_a, x_b, y_b}, a = (2p)*1024+t, b = (2p+1)*1024+t.
  // One ds_read_b128 per pair (8 per thread per iteration).
  __shared__ float4 s_p[N_ / 2];
  // parity-double-buffered per-wave argmax keys: one barrier per iteration
  __shared__ unsigned long long s_key[2][NW_];

  const float* xb  = x + (size_t)b * (N_ * 3);
  float* out_x     = out;                        // [B*K*3] f32 (bf16-grid values)
  float* out_batch = out + (size_t)B_ * K_ * 3;  // [B*K]   f32 cloud ids

  // batch output (buffer re-poisoned every call -> rewrite every call)
  {
    const float bb = (float)b;
    for (int i = t; i < K_; i += THREADS_) out_batch[b * K_ + i] = bb;
  }

  // z and running-min in named registers; x,y staged to LDS
#define DECLP(i) float pz##i, m##i;
  PTS_LIST(DECLP)
#undef DECLP

#define LOADP(p, A, B) {                                              \
      const float* a_ = xb + 3 * ((A) * THREADS_ + t);                \
      const float* b_ = xb + 3 * ((B) * THREADS_ + t);                \
      float4 v_;                                                      \
      v_.x = a_[0]; v_.y = a_[1];                                     \
      v_.z = b_[0]; v_.w = b_[1];                                     \
      s_p[(p) * THREADS_ + t] = v_;                                   \
      pz##A = a_[2]; pz##B = b_[2];                                   \
      m##A = __builtin_inff(); m##B = __builtin_inff(); }
  PAIR_LIST(LOADP)
#undef LOADP

  // dist update for a pair (bit-exact FMA-V1 per point, same order as R19)
#define UPD(p, A, B) {                                                          \
      const float4 v_ = s_p[(p) * THREADS_ + t];                                \
      { const float dx_ = v_.x - cx;                                            \
        const float dy_ = v_.y - cy;                                            \
        const float dz_ = pz##A - cz;                                           \
        const float d_  = __builtin_fmaf(dz_, dz_,                              \
                          __builtin_fmaf(dx_, dx_, dy_ * dy_));                 \
        m##A = fminf(m##A, d_); }                                               \
      { const float dx_ = v_.z - cx;                                            \
        const float dy_ = v_.w - cy;                                            \
        const float dz_ = pz##B - cz;                                           \
        const float d_  = __builtin_fmaf(dz_, dz_,                              \
                          __builtin_fmaf(dx_, dx_, dy_ * dy_));                 \
        m##B = fminf(m##B, d_); } }

  // max3 tree over the 16 m values; value identical to sequential max.
#define MAXTREE(M_) { const float t0_ = fmaxf(fmaxf(m0,  m1),  m2);  \
                      const float t1_ = fmaxf(fmaxf(m3,  m4),  m5);  \
                      const float t2_ = fmaxf(fmaxf(m6,  m7),  m8);  \
                      const float t3_ = fmaxf(fmaxf(m9,  m10), m11); \
                      const float t4_ = fmaxf(fmaxf(m12, m13), m14); \
                      const float u0_ = fmaxf(fmaxf(t0_, t1_), t2_); \
                      const float u1_ = fmaxf(fmaxf(t3_, t4_), m15); \
                      M_ = fmaxf(u0_, u1_); }

  // descending equality chain: final bs = smallest slot with m==M
#define IDXCHAIN(M_, BS_) { BS_ = 15;                                \
      if (m14 == M_) BS_ = 14; if (m13 == M_) BS_ = 13;              \
      if (m12 == M_) BS_ = 12; if (m11 == M_) BS_ = 11;              \
      if (m10 == M_) BS_ = 10; if (m9  == M_) BS_ = 9;               \
      if (m8  == M_) BS_ = 8;  if (m7  == M_) BS_ = 7;               \
      if (m6  == M_) BS_ = 6;  if (m5  == M_) BS_ = 5;               \
      if (m4  == M_) BS_ = 4;  if (m3  == M_) BS_ = 3;               \
      if (m2  == M_) BS_ = 2;  if (m1  == M_) BS_ = 1;               \
      if (m0  == M_) BS_ = 0; }

  // per-thread argmax -> wave argmax -> per-wave key in LDS
#define REDUCE_AND_POST(PARITY) {                                        \
      float bv; int bs;                                                  \
      MAXTREE(bv)                                                        \
      IDXCHAIN(bv, bs)                                                   \
      const unsigned bg = (unsigned)(bs * THREADS_ + t);                 \
      float wv; unsigned wg;                                             \
      wave_argmax(bv, bg, wv, wg);                                       \
      if (lane == 0) {                                                   \
        union { float f; unsigned u; } cv; cv.f = wv;                    \
        s_key[PARITY][wave] =                                            \
            ((unsigned long long)cv.u << 32) | (unsigned)~wg;            \
      } }

  // ---- iteration 0: seed = point 0 ----
  float cx = xb[0], cy = xb[1], cz = xb[2];
  if (t == 0) {
    const uint64_t o = ((uint64_t)b * K_) * 3;
    out_x[o + 0] = bfr(cx); out_x[o + 1] = bfr(cy); out_x[o + 2] = bfr(cz);
  }

  PAIR_LIST(UPD)                     // m_i = d_i (min with +inf)
  REDUCE_AND_POST(0)
  __syncthreads();

  // ---- iterations 1..K-1 ----
  for (int j = 1; j < K_; ++j) {
    const int rp = (j - 1) & 1;
    const int wp = j & 1;

    // finalize block argmax: 16 per-wave keys broadcast (lane&15), 4 DPP
    // levels within each 16-lane row -> every lane holds the block winner.
    unsigned long long k = s_key[rp][lane & 15];
    k = kmax_dpp<0xB1>(k);    // quad_perm lane^1
    k = kmax_dpp<0x4E>(k);    // quad_perm lane^2
    k = kmax_dpp<0x141>(k);   // row_half_mirror (lane^7, covers ^4)
    k = kmax_dpp<0x140>(k);   // row_mirror (lane^15, covers ^8)
    const unsigned idx = ~(unsigned)k;           // winner global point index
    const int gu = __builtin_amdgcn_readfirstlane((int)idx);

    // center: x,y from the pair record (uniform broadcast read + 2 selects),
    // z from global (L2; latency hides under the cz-independent xy VALU)
    const int tg   = gu & (THREADS_ - 1);
    const int slot = gu >> 10;
    const float4 c4 = s_p[(slot >> 1) * THREADS_ + tg];
    const bool hi = (slot & 1) != 0;
    cx = hi ? c4.z : c4.x;
    cy = hi ? c4.w : c4.y;
    cz = xb[3 * gu + 2];
    if (t == 0) {
      const uint64_t o = ((uint64_t)b * K_ + j) * 3;
      out_x[o + 0] = bfr(cx); out_x[o + 1] = bfr(cy); out_x[o + 2] = bfr(cz);
    }

    // update mind + per-thread/wave argmax for next round
    PAIR_LIST(UPD)
    REDUCE_AND_POST(wp)
    __syncthreads();
  }
#undef UPD
#undef MAXTREE
#undef IDXCHAIN
#undef REDUCE_AND_POST

}

extern "C" void kernel_launch(void* const* d_in, const int* in_sizes, int n_in,
                              void* d_out, int out_size, void* d_ws, size_t ws_size,
                              hipStream_t stream) {
  const float* x = (const float*)d_in[0];  // f32, [B*N, 3]
  float* out     = (float*)d_out;          // f32: [B*K*3] coords + [B*K] batch
  (void)in_sizes; (void)n_in; (void)out_size; (void)d_ws; (void)ws_size;
  hipLaunchKernelGGL(fps_kernel, dim3(B_), dim3(THREADS_), 0, stream, x, out);
}